// Round 2
// baseline (754.325 us; speedup 1.0000x reference)
//
#include <hip/hip_runtime.h>

// ---------------------------------------------------------------------------
// Face detection pipeline, all fp32 (no fp32 MFMA on CDNA4 -> vector ALU).
// Stages: conv1..conv4 (stride2, relu) -> head conv (stride1) -> decode ->
// rank/top-100 -> sequential NMS -> draw borders.
// ---------------------------------------------------------------------------

constexpr int NANCH = 12288;   // 64*64*3
constexpr int KTOP  = 100;

// ---------------- stride-2 3x3 SAME conv + relu ----------------------------
// SAME w/ stride2, k=3, even in: pad_lo=0, pad_hi=1  (XLA formula)
template<int CIN, int HIN, int WIN, int COB>
__global__ __launch_bounds__(256)
void conv_s2(const float* __restrict__ in, const float* __restrict__ w,
             const float* __restrict__ bias, float* __restrict__ out)
{
    constexpr int HOUT = HIN / 2, WOUT = WIN / 2;
    const int px = blockIdx.x * 256 + threadIdx.x;
    const int oy = px / WOUT, ox = px % WOUT;
    const int co0 = blockIdx.y * COB;

    float acc[COB];
#pragma unroll
    for (int c = 0; c < COB; ++c) acc[c] = 0.f;

    const int iy0 = oy * 2, ix0 = ox * 2;
    for (int ci = 0; ci < CIN; ++ci) {
        const float* __restrict__ ip = in + ci * (HIN * WIN);
        float v[9];
#pragma unroll
        for (int ky = 0; ky < 3; ++ky) {
            const int iy = iy0 + ky;
            const bool yok = (iy < HIN);
#pragma unroll
            for (int kx = 0; kx < 3; ++kx) {
                const int ix = ix0 + kx;
                v[ky * 3 + kx] = (yok && ix < WIN) ? ip[iy * WIN + ix] : 0.f;
            }
        }
        // weight index is wave-uniform -> expect s_load scalarization
#pragma unroll
        for (int co = 0; co < COB; ++co) {
#pragma unroll
            for (int k = 0; k < 9; ++k)
                acc[co] = fmaf(v[k], w[((co0 + co) * CIN + ci) * 9 + k], acc[co]);
        }
    }
#pragma unroll
    for (int co = 0; co < COB; ++co) {
        float r = fmaxf(acc[co] + bias[co0 + co], 0.f);
        out[(co0 + co) * (HOUT * WOUT) + oy * WOUT + ox] = r;
    }
}

// ---------------- head conv (stride1, pad1), ci-split partials -------------
// in: 256x64x64, w: (15,256,3,3). part[cs][15][4096], cs = ci-chunk of 32.
__global__ __launch_bounds__(256)
void head_part(const float* __restrict__ in, const float* __restrict__ w,
               float* __restrict__ part)
{
    const int px = blockIdx.x * 256 + threadIdx.x;   // 0..4095
    const int oy = px >> 6, ox = px & 63;
    const int cs = blockIdx.y;                       // 0..7

    float acc[15];
#pragma unroll
    for (int c = 0; c < 15; ++c) acc[c] = 0.f;

    for (int ci = cs * 32; ci < cs * 32 + 32; ++ci) {
        const float* __restrict__ ip = in + ci * 4096;
        float v[9];
#pragma unroll
        for (int ky = 0; ky < 3; ++ky) {
            const int iy = oy + ky - 1;
            const bool yok = (iy >= 0) && (iy < 64);
#pragma unroll
            for (int kx = 0; kx < 3; ++kx) {
                const int ix = ox + kx - 1;
                v[ky * 3 + kx] = (yok && ix >= 0 && ix < 64) ? ip[iy * 64 + ix] : 0.f;
            }
        }
#pragma unroll
        for (int co = 0; co < 15; ++co) {
#pragma unroll
            for (int k = 0; k < 9; ++k)
                acc[co] = fmaf(v[k], w[(co * 256 + ci) * 9 + k], acc[co]);
        }
    }
#pragma unroll
    for (int co = 0; co < 15; ++co)
        part[(cs * 15 + co) * 4096 + px] = acc[co];
}

__global__ void head_reduce(const float* __restrict__ part,
                            const float* __restrict__ bias,
                            float* __restrict__ out)
{
    const int t = blockIdx.x * 256 + threadIdx.x;    // < 61440
    const int co = t >> 12, px = t & 4095;
    float s = 0.f;
#pragma unroll
    for (int c = 0; c < 8; ++c) s += part[(c * 15 + co) * 4096 + px];
    out[co * 4096 + px] = s + bias[co];
}

// ---------------- anchor decode + sortable key -----------------------------
__global__ void decode_kernel(const float* __restrict__ head,
                              float4* __restrict__ boxes,
                              unsigned long long* __restrict__ keys)
{
    const int i = blockIdx.x * 256 + threadIdx.x;    // < 12288
    const int a = i % 3;
    const int xy = i / 3;
    const int x = xy & 63, y = xy >> 6;
    const int px = y * 64 + x;

    const float t0 = head[(a * 5 + 0) * 4096 + px];
    const float t1 = head[(a * 5 + 1) * 4096 + px];
    const float t2 = head[(a * 5 + 2) * 4096 + px];
    const float t3 = head[(a * 5 + 3) * 4096 + px];
    const float lg = head[(a * 5 + 4) * 4096 + px];

    const float sz  = (a == 0) ? 32.f : (a == 1) ? 64.f : 128.f;
    const float cxa = (x + 0.5f) * 16.f;
    const float cya = (y + 0.5f) * 16.f;

    // force unfused mul/add to mirror reference elementwise ops
    const float cx = __fadd_rn(cxa, __fmul_rn(t0, sz));
    const float cy = __fadd_rn(cya, __fmul_rn(t1, sz));
    const float bw = __fmul_rn(sz, expf(fminf(fmaxf(t2, -4.f), 4.f)));
    const float bh = __fmul_rn(sz, expf(fminf(fmaxf(t3, -4.f), 4.f)));
    const float hw = __fmul_rn(bw, 0.5f);
    const float hh = __fmul_rn(bh, 0.5f);

    float4 bb;
    bb.x = __fsub_rn(cx, hw);
    bb.y = __fsub_rn(cy, hh);
    bb.z = __fadd_rn(cx, hw);
    bb.w = __fadd_rn(cy, hh);
    boxes[i] = bb;

    const float score = 1.f / (1.f + expf(-lg));
    unsigned long long key = 0ull;
    if (score >= 0.5f) {  // valid; positive float bits are order-preserving
        key = ((unsigned long long)__float_as_uint(score) << 32)
            | (unsigned long long)(0xFFFFFFFFu - (unsigned)i);  // stable tiebreak
    }
    keys[i] = key;
}

// ---------------- exact rank among all keys (j-split, readlane bcast) ------
constexpr int JSPLIT = 16;
constexpr int JCHUNK = NANCH / JSPLIT;   // 768

__global__ __launch_bounds__(256)
void rank_kernel(const unsigned long long* __restrict__ keys,
                 int* __restrict__ rank)
{
    const int i = blockIdx.x * 256 + threadIdx.x;
    const unsigned long long ki = keys[i];
    const int lane = threadIdx.x & 63;
    const int jbase = blockIdx.y * JCHUNK;

    int cnt = 0;
    for (int g = 0; g < JCHUNK / 64; ++g) {
        const unsigned long long kj = keys[jbase + g * 64 + lane];
        const unsigned lo0 = (unsigned)kj;
        const unsigned hi0 = (unsigned)(kj >> 32);
#pragma unroll
        for (int l = 0; l < 64; ++l) {
            const unsigned lo = (unsigned)__builtin_amdgcn_readlane((int)lo0, l);
            const unsigned hi = (unsigned)__builtin_amdgcn_readlane((int)hi0, l);
            const unsigned long long kjj = ((unsigned long long)hi << 32) | lo;
            cnt += (kjj > ki) ? 1 : 0;
        }
    }
    if (cnt) atomicAdd(&rank[i], cnt);   // int atomics: deterministic
}

__global__ void scatter_kernel(const unsigned long long* __restrict__ keys,
                               const int* __restrict__ rank,
                               const float4* __restrict__ boxes,
                               float4* __restrict__ selb, int* __restrict__ selv)
{
    const int i = blockIdx.x * 256 + threadIdx.x;
    if (keys[i] == 0ull) return;            // below score threshold
    const int r = rank[i];
    if (r < KTOP) { selb[r] = boxes[i]; selv[r] = 1; }
}

// ---------------- sequential NMS (exact reference semantics) ---------------
__global__ __launch_bounds__(128)
void nms_kernel(const float4* __restrict__ selb, const int* __restrict__ selv,
                float4* __restrict__ drawb)
{
    __shared__ float bx1[KTOP], by1[KTOP], bx2[KTOP], by2[KTOP], ar[KTOP];
    __shared__ int kp[KTOP];
    const int t = threadIdx.x;
    if (t < KTOP) {
        const float4 b = selb[t];
        bx1[t] = b.x; by1[t] = b.y; bx2[t] = b.z; by2[t] = b.w;
        ar[t] = (b.z - b.x) * (b.w - b.y);
        kp[t] = selv[t];
    }
    __syncthreads();
    for (int i = 0; i < KTOP - 1; ++i) {
        if (t > i && t < KTOP) {
            if (kp[i] && kp[t]) {
                const float lx = fmaxf(bx1[i], bx1[t]);
                const float ly = fmaxf(by1[i], by1[t]);
                const float rx = fminf(bx2[i], bx2[t]);
                const float ry = fminf(by2[i], by2[t]);
                const float ww = fmaxf(rx - lx, 0.f);
                const float hh = fmaxf(ry - ly, 0.f);
                const float inter = ww * hh;
                const float iou = inter / (ar[i] + ar[t] - inter + 1e-9f);
                if (iou > 0.5f) kp[t] = 0;
            }
        }
        __syncthreads();
    }
    if (t < KTOP) {
        float4 d;
        if (kp[t]) {
            d.x = fminf(fmaxf(bx1[t], 0.f), 1024.f);
            d.y = fminf(fmaxf(by1[t], 0.f), 1024.f);
            d.z = fminf(fmaxf(bx2[t], 0.f), 1024.f);
            d.w = fminf(fmaxf(by2[t], 0.f), 1024.f);
        } else {  // sentinel: never matches any pixel
            d.x = 3e9f; d.y = 3e9f; d.z = -3e9f; d.w = -3e9f;
        }
        drawb[t] = d;
    }
}

// ---------------- draw red borders -----------------------------------------
__global__ __launch_bounds__(256)
void draw_kernel(const float* __restrict__ frame,
                 const float4* __restrict__ drawb, float* __restrict__ out)
{
    const int y = blockIdx.x >> 2;
    const int x = ((blockIdx.x & 3) << 8) + threadIdx.x;
    const float fy = (float)y, fx = (float)x;

    bool mask = false;
#pragma unroll 1
    for (int b = 0; b < KTOP; ++b) {
        const float4 d = drawb[b];            // wave-uniform
        if (fy >= d.y && fy < d.w) {          // scalar branch: y-row inside box?
            const bool yinner = (fy >= d.y + 4.f) && (fy < d.w - 4.f);
            const bool xin    = (fx >= d.x) && (fx < d.z);
            const bool xinner = (fx >= d.x + 4.f) && (fx < d.z - 4.f);
            mask |= xin && !(yinner && xinner);
        }
    }
    const int p = y * 1024 + x;
    const float f0 = frame[p];
    const float f1 = frame[1048576 + p];
    const float f2 = frame[2097152 + p];
    out[p]           = mask ? 1.f : f0;
    out[1048576 + p] = mask ? 0.f : f1;
    out[2097152 + p] = mask ? 0.f : f2;
}

// ---------------------------------------------------------------------------
extern "C" void kernel_launch(void* const* d_in, const int* in_sizes, int n_in,
                              void* d_out, int out_size, void* d_ws, size_t ws_size,
                              hipStream_t stream)
{
    const float* frame = (const float*)d_in[0];
    const float* w1 = (const float*)d_in[1];  const float* b1 = (const float*)d_in[2];
    const float* w2 = (const float*)d_in[3];  const float* b2 = (const float*)d_in[4];
    const float* w3 = (const float*)d_in[5];  const float* b3 = (const float*)d_in[6];
    const float* w4 = (const float*)d_in[7];  const float* b4 = (const float*)d_in[8];
    const float* wh = (const float*)d_in[9];  const float* bh = (const float*)d_in[10];

    char* ws = (char*)d_ws;
    // Region 1 (33.55 MB): buf1, later reused for buf3 + buf4
    float* buf1 = (float*)(ws);                          // 32*512*512
    float* buf3 = (float*)(ws);                          // 128*128*128 (reuse)
    float* buf4 = (float*)(ws + 8388608);                // 256*64*64   (reuse)
    // Region 2 (16.78 MB @ +33554432): buf2, later reused for head/nms data
    const size_t R2 = 33554432;
    float* buf2  = (float*)(ws + R2);                    // 64*256*256
    float* bufP  = (float*)(ws + R2);                    // 8*15*4096 partials (reuse)
    float* heado = (float*)(ws + R2 + 2097152);          // 15*4096
    float4* boxes = (float4*)(ws + R2 + 2359296);        // 12288*4
    unsigned long long* keys = (unsigned long long*)(ws + R2 + 2555904); // 12288*8
    int*    rankb = (int*)(ws + R2 + 2654208);           // 12288 ints
    int*    selv  = (int*)(ws + R2 + 2703360);           // 100 ints
    float4* selb  = (float4*)(ws + R2 + 2703872);        // 100 float4
    float4* drawb = (float4*)(ws + R2 + 2705472);        // 100 float4
    float*  outp  = (float*)d_out;

    // backbone
    conv_s2<3, 1024, 1024, 32><<<dim3(1024, 1), 256, 0, stream>>>(frame, w1, b1, buf1);
    conv_s2<32,  512,  512, 32><<<dim3(256, 2), 256, 0, stream>>>(buf1, w2, b2, buf2);
    conv_s2<64,  256,  256, 16><<<dim3(64, 8), 256, 0, stream>>>(buf2, w3, b3, buf3);
    conv_s2<128, 128,  128, 16><<<dim3(16, 16), 256, 0, stream>>>(buf3, w4, b4, buf4);

    // head
    head_part<<<dim3(16, 8), 256, 0, stream>>>(buf4, wh, bufP);
    head_reduce<<<240, 256, 0, stream>>>(bufP, bh, heado);

    // zero rank+selv (placed after buf2 region is dead)
    hipMemsetAsync(rankb, 0, 49152 + 512, stream);

    // decode + top-100 + nms + draw
    decode_kernel<<<48, 256, 0, stream>>>(heado, boxes, keys);
    rank_kernel<<<dim3(48, JSPLIT), 256, 0, stream>>>(keys, rankb);
    scatter_kernel<<<48, 256, 0, stream>>>(keys, rankb, boxes, selb, selv);
    nms_kernel<<<1, 128, 0, stream>>>(selb, selv, drawb);
    draw_kernel<<<4096, 256, 0, stream>>>(frame, drawb, outp);
}

// Round 3
// 450.787 us; speedup vs baseline: 1.6734x; 1.6734x over previous
//
#include <hip/hip_runtime.h>

// ---------------------------------------------------------------------------
// Face detection pipeline, all fp32 (no fp32 MFMA on CDNA4 -> vector ALU).
// Round 3: fix latency-bound convs (was 12% occupancy, 6% VALUBusy) by
// ci-chunk splitting + smaller COB -> >=2048 blocks per conv (32 waves/CU),
// partial sums in fp32 + reduce kernel applying bias/relu.
// ---------------------------------------------------------------------------

constexpr int KTOP  = 100;
constexpr int NANCH = 12288;   // 64*64*3

// ---------------- generic 3x3 SAME conv (stride 1 or 2) --------------------
// FUSEOUT=true: write relu(acc+bias) to out[co*NPX+px]
// FUSEOUT=false: write raw partial to out[(chunk*CO+co)*NPX+px]
template<int CIN, int HIN, int WIN, int STRIDE, int COB, int CICHUNK, bool FUSEOUT>
__global__ __launch_bounds__(256)
void convk(const float* __restrict__ in, const float* __restrict__ w,
           const float* __restrict__ bias, float* __restrict__ out, int CO)
{
    constexpr int HOUT = (STRIDE == 2) ? HIN / 2 : HIN;
    constexpr int WOUT = (STRIDE == 2) ? WIN / 2 : WIN;
    constexpr int PADLO = (STRIDE == 1) ? 1 : 0;   // XLA SAME: s2/k3/even -> (0,1)
    constexpr int NPX = HOUT * WOUT;

    const int px = blockIdx.x * 256 + threadIdx.x;
    const int oy = px / WOUT, ox = px % WOUT;
    const int co0 = blockIdx.y * COB;
    const int ci0 = blockIdx.z * CICHUNK;

    float acc[COB];
#pragma unroll
    for (int c = 0; c < COB; ++c) acc[c] = 0.f;

    const int iy0 = oy * STRIDE - PADLO, ix0 = ox * STRIDE - PADLO;
#pragma unroll 2
    for (int ci = ci0; ci < ci0 + CICHUNK; ++ci) {
        const float* __restrict__ ip = in + ci * (HIN * WIN);
        float v[9];
#pragma unroll
        for (int ky = 0; ky < 3; ++ky) {
            const int iy = iy0 + ky;
            const bool yok = (iy >= 0) && (iy < HIN);
#pragma unroll
            for (int kx = 0; kx < 3; ++kx) {
                const int ix = ix0 + kx;
                v[ky * 3 + kx] = (yok && ix >= 0 && ix < WIN) ? ip[iy * WIN + ix] : 0.f;
            }
        }
        // wave-uniform weight index -> s_load scalarization (verified r2: VGPR=24)
#pragma unroll
        for (int co = 0; co < COB; ++co) {
            const float* __restrict__ wp = w + ((co0 + co) * CIN + ci) * 9;
#pragma unroll
            for (int k = 0; k < 9; ++k)
                acc[co] = fmaf(v[k], wp[k], acc[co]);
        }
    }
    if constexpr (FUSEOUT) {
#pragma unroll
        for (int co = 0; co < COB; ++co)
            out[(co0 + co) * NPX + px] = fmaxf(acc[co] + bias[co0 + co], 0.f);
    } else {
#pragma unroll
        for (int co = 0; co < COB; ++co)
            out[(blockIdx.z * CO + co0 + co) * NPX + px] = acc[co];
    }
}

// ---------------- chunk reduction + bias (+relu) ---------------------------
template<int NCHUNK, int NPX, bool RELU>
__global__ __launch_bounds__(256)
void reducek(const float* __restrict__ part, const float* __restrict__ bias,
             float* __restrict__ out, int CO)
{
    const int t = blockIdx.x * 256 + threadIdx.x;   // < CO*NPX
    const int co = t / NPX, px = t - co * NPX;
    float s = 0.f;
#pragma unroll
    for (int c = 0; c < NCHUNK; ++c) s += part[(c * CO + co) * NPX + px];
    s += bias[co];
    out[co * NPX + px] = RELU ? fmaxf(s, 0.f) : s;
}

// ---------------- anchor decode + sortable key -----------------------------
__global__ void decode_kernel(const float* __restrict__ head,
                              float4* __restrict__ boxes,
                              unsigned long long* __restrict__ keys)
{
    const int i = blockIdx.x * 256 + threadIdx.x;    // < 12288
    const int a = i % 3;
    const int xy = i / 3;
    const int x = xy & 63, y = xy >> 6;
    const int px = y * 64 + x;

    const float t0 = head[(a * 5 + 0) * 4096 + px];
    const float t1 = head[(a * 5 + 1) * 4096 + px];
    const float t2 = head[(a * 5 + 2) * 4096 + px];
    const float t3 = head[(a * 5 + 3) * 4096 + px];
    const float lg = head[(a * 5 + 4) * 4096 + px];

    const float sz  = (a == 0) ? 32.f : (a == 1) ? 64.f : 128.f;
    const float cxa = (x + 0.5f) * 16.f;
    const float cya = (y + 0.5f) * 16.f;

    const float cx = __fadd_rn(cxa, __fmul_rn(t0, sz));
    const float cy = __fadd_rn(cya, __fmul_rn(t1, sz));
    const float bw = __fmul_rn(sz, expf(fminf(fmaxf(t2, -4.f), 4.f)));
    const float bh = __fmul_rn(sz, expf(fminf(fmaxf(t3, -4.f), 4.f)));
    const float hw = __fmul_rn(bw, 0.5f);
    const float hh = __fmul_rn(bh, 0.5f);

    float4 bb;
    bb.x = __fsub_rn(cx, hw);
    bb.y = __fsub_rn(cy, hh);
    bb.z = __fadd_rn(cx, hw);
    bb.w = __fadd_rn(cy, hh);
    boxes[i] = bb;

    const float score = 1.f / (1.f + expf(-lg));
    unsigned long long key = 0ull;
    if (score >= 0.5f) {  // positive float bits are order-preserving
        key = ((unsigned long long)__float_as_uint(score) << 32)
            | (unsigned long long)(0xFFFFFFFFu - (unsigned)i);  // stable tiebreak
    }
    keys[i] = key;
}

// ---------------- exact rank among all keys (j-split, readlane bcast) ------
constexpr int JSPLIT = 16;
constexpr int JCHUNK = NANCH / JSPLIT;   // 768

__global__ __launch_bounds__(256)
void rank_kernel(const unsigned long long* __restrict__ keys,
                 int* __restrict__ rank)
{
    const int i = blockIdx.x * 256 + threadIdx.x;
    const unsigned long long ki = keys[i];
    const int lane = threadIdx.x & 63;
    const int jbase = blockIdx.y * JCHUNK;

    int cnt = 0;
    for (int g = 0; g < JCHUNK / 64; ++g) {
        const unsigned long long kj = keys[jbase + g * 64 + lane];
        const unsigned lo0 = (unsigned)kj;
        const unsigned hi0 = (unsigned)(kj >> 32);
#pragma unroll
        for (int l = 0; l < 64; ++l) {
            const unsigned lo = (unsigned)__builtin_amdgcn_readlane((int)lo0, l);
            const unsigned hi = (unsigned)__builtin_amdgcn_readlane((int)hi0, l);
            const unsigned long long kjj = ((unsigned long long)hi << 32) | lo;
            cnt += (kjj > ki) ? 1 : 0;
        }
    }
    if (cnt) atomicAdd(&rank[i], cnt);   // int atomics: deterministic
}

__global__ void scatter_kernel(const unsigned long long* __restrict__ keys,
                               const int* __restrict__ rank,
                               const float4* __restrict__ boxes,
                               float4* __restrict__ selb, int* __restrict__ selv)
{
    const int i = blockIdx.x * 256 + threadIdx.x;
    if (keys[i] == 0ull) return;            // below score threshold
    const int r = rank[i];
    if (r < KTOP) { selb[r] = boxes[i]; selv[r] = 1; }
}

// ---------------- sequential NMS (exact reference semantics) ---------------
__global__ __launch_bounds__(128)
void nms_kernel(const float4* __restrict__ selb, const int* __restrict__ selv,
                float4* __restrict__ drawb)
{
    __shared__ float bx1[KTOP], by1[KTOP], bx2[KTOP], by2[KTOP], ar[KTOP];
    __shared__ int kp[KTOP];
    const int t = threadIdx.x;
    if (t < KTOP) {
        const float4 b = selb[t];
        bx1[t] = b.x; by1[t] = b.y; bx2[t] = b.z; by2[t] = b.w;
        ar[t] = (b.z - b.x) * (b.w - b.y);
        kp[t] = selv[t];
    }
    __syncthreads();
    for (int i = 0; i < KTOP - 1; ++i) {
        if (t > i && t < KTOP) {
            if (kp[i] && kp[t]) {
                const float lx = fmaxf(bx1[i], bx1[t]);
                const float ly = fmaxf(by1[i], by1[t]);
                const float rx = fminf(bx2[i], bx2[t]);
                const float ry = fminf(by2[i], by2[t]);
                const float ww = fmaxf(rx - lx, 0.f);
                const float hh = fmaxf(ry - ly, 0.f);
                const float inter = ww * hh;
                const float iou = inter / (ar[i] + ar[t] - inter + 1e-9f);
                if (iou > 0.5f) kp[t] = 0;
            }
        }
        __syncthreads();
    }
    if (t < KTOP) {
        float4 d;
        if (kp[t]) {
            d.x = fminf(fmaxf(bx1[t], 0.f), 1024.f);
            d.y = fminf(fmaxf(by1[t], 0.f), 1024.f);
            d.z = fminf(fmaxf(bx2[t], 0.f), 1024.f);
            d.w = fminf(fmaxf(by2[t], 0.f), 1024.f);
        } else {  // sentinel: never matches any pixel
            d.x = 3e9f; d.y = 3e9f; d.z = -3e9f; d.w = -3e9f;
        }
        drawb[t] = d;
    }
}

// ---------------- draw red borders -----------------------------------------
__global__ __launch_bounds__(256)
void draw_kernel(const float* __restrict__ frame,
                 const float4* __restrict__ drawb, float* __restrict__ out)
{
    const int y = blockIdx.x >> 2;
    const int x = ((blockIdx.x & 3) << 8) + threadIdx.x;
    const float fy = (float)y, fx = (float)x;

    bool mask = false;
#pragma unroll 1
    for (int b = 0; b < KTOP; ++b) {
        const float4 d = drawb[b];            // wave-uniform
        if (fy >= d.y && fy < d.w) {          // scalar branch: y-row inside box?
            const bool yinner = (fy >= d.y + 4.f) && (fy < d.w - 4.f);
            const bool xin    = (fx >= d.x) && (fx < d.z);
            const bool xinner = (fx >= d.x + 4.f) && (fx < d.z - 4.f);
            mask |= xin && !(yinner && xinner);
        }
    }
    const int p = y * 1024 + x;
    const float f0 = frame[p];
    const float f1 = frame[1048576 + p];
    const float f2 = frame[2097152 + p];
    out[p]           = mask ? 1.f : f0;
    out[1048576 + p] = mask ? 0.f : f1;
    out[2097152 + p] = mask ? 0.f : f2;
}

// ---------------------------------------------------------------------------
extern "C" void kernel_launch(void* const* d_in, const int* in_sizes, int n_in,
                              void* d_out, int out_size, void* d_ws, size_t ws_size,
                              hipStream_t stream)
{
    const float* frame = (const float*)d_in[0];
    const float* w1 = (const float*)d_in[1];  const float* b1 = (const float*)d_in[2];
    const float* w2 = (const float*)d_in[3];  const float* b2 = (const float*)d_in[4];
    const float* w3 = (const float*)d_in[5];  const float* b3 = (const float*)d_in[6];
    const float* w4 = (const float*)d_in[7];  const float* b4 = (const float*)d_in[8];
    const float* wh = (const float*)d_in[9];  const float* bh = (const float*)d_in[10];

    char* ws = (char*)d_ws;
    // Region A [0, 33.55M), Region B [33.55M, 50.33M). Lifetimes audited:
    float* buf1  = (float*)ws;                   // conv1 out 33.55M  [A]
    float* buf2  = (float*)(ws + 33554432);      // conv2 out 16.78M  [B]
    float* part3 = (float*)ws;                   // 2x8.39M = 16.78M  [A, buf1 dead]
    float* buf3  = (float*)(ws + 16777216);      // 8.39M             [A hi]
    float* part4 = (float*)(ws + 33554432);      // 4x4.19M = 16.78M  [B, buf2 dead]
    float* buf4  = (float*)ws;                   // 4.19M             [A, part3 dead]
    float* partH = (float*)(ws + 8388608);       // 16x15x4096x4 = 3.93M [A mid]
    float* heado = (float*)(ws + 16777216);      // 245K              [A, buf3 dead]
    char*  B     = ws + 33554432;                // [B, part4 dead after conv4red]
    float4* boxes = (float4*)(B);                                  // 196608
    unsigned long long* keys = (unsigned long long*)(B + 196608);  // 98304
    int*    rankb = (int*)(B + 294912);                            // 49152
    int*    selv  = (int*)(B + 344064);                            // 512
    float4* selb  = (float4*)(B + 344576);                         // 1600
    float4* drawb = (float4*)(B + 346176);                         // 1600
    float*  outp  = (float*)d_out;

    // backbone: grids sized for >=8 blocks/CU on the big convs
    convk<3, 1024, 1024, 2, 8, 3,  true ><<<dim3(1024, 4, 1), 256, 0, stream>>>(frame, w1, b1, buf1, 32);
    convk<32, 512,  512, 2, 8, 32, true ><<<dim3(256,  8, 1), 256, 0, stream>>>(buf1, w2, b2, buf2, 64);
    convk<64, 256,  256, 2, 8, 32, false><<<dim3(64,  16, 2), 256, 0, stream>>>(buf2, w3, nullptr, part3, 128);
    reducek<2, 16384, true><<<8192, 256, 0, stream>>>(part3, b3, buf3, 128);
    convk<128, 128, 128, 2, 8, 32, false><<<dim3(16,  32, 4), 256, 0, stream>>>(buf3, w4, nullptr, part4, 256);
    reducek<4, 4096, true><<<4096, 256, 0, stream>>>(part4, b4, buf4, 256);

    // head (no relu)
    convk<256, 64, 64, 1, 5, 16, false><<<dim3(16, 3, 16), 256, 0, stream>>>(buf4, wh, nullptr, partH, 15);
    reducek<16, 4096, false><<<240, 256, 0, stream>>>(partH, bh, heado, 15);

    // zero rank+selv (B region dead after conv4red)
    hipMemsetAsync(rankb, 0, 49152 + 512, stream);

    // decode + top-100 + nms + draw
    decode_kernel<<<48, 256, 0, stream>>>(heado, boxes, keys);
    rank_kernel<<<dim3(48, JSPLIT), 256, 0, stream>>>(keys, rankb);
    scatter_kernel<<<48, 256, 0, stream>>>(keys, rankb, boxes, selb, selv);
    nms_kernel<<<1, 128, 0, stream>>>(selb, selv, drawb);
    draw_kernel<<<4096, 256, 0, stream>>>(frame, drawb, outp);
}

// Round 6
// 423.732 us; speedup vs baseline: 1.7802x; 1.0638x over previous
//
#include <hip/hip_runtime.h>

// ---------------------------------------------------------------------------
// Face detection pipeline, all fp32 (no fp32 MFMA on CDNA4 -> vector ALU).
// Round 4 (2nd resubmit; infra timeouts): register-block 4 output px/thread
// (float4 input loads) to raise FMA:load ratio ~4x; COB=4 keeps grids at
// 1024 blocks without extra splits.
// ---------------------------------------------------------------------------

constexpr int KTOP  = 100;
constexpr int NANCH = 12288;   // 64*64*3

// ---------------- generic 3x3 SAME conv, PXT output px per thread ----------
// STRIDE==2: PXT==4, pad (0,1).  STRIDE==1: PXT==1, pad (1,1).
// FUSEOUT=true: out[co*NPX+px] = relu(acc+bias)
// FUSEOUT=false: out[(blockIdx.z*CO+co)*NPX+px] = raw partial
template<int CIN, int HIN, int WIN, int STRIDE, int PXT, int COB, int CICHUNK, bool FUSEOUT>
__global__ __launch_bounds__(256)
void convk(const float* __restrict__ in, const float* __restrict__ w,
           const float* __restrict__ bias, float* __restrict__ out, int CO)
{
    constexpr int HOUT = (STRIDE == 2) ? HIN / 2 : HIN;
    constexpr int WOUT = (STRIDE == 2) ? WIN / 2 : WIN;
    constexpr int NPX  = HOUT * WOUT;
    constexpr int GPR  = WOUT / PXT;                 // pixel-groups per row
    constexpr int NCOL = (STRIDE == 2) ? 2 * PXT + 1 : PXT + 2;

    const int g   = blockIdx.x * 256 + threadIdx.x;  // pixel-group id
    const int oy  = g / GPR;
    const int oxb = (g - oy * GPR) * PXT;
    const int co0 = blockIdx.y * COB;
    const int ci0 = blockIdx.z * CICHUNK;

    float acc[COB][PXT];
#pragma unroll
    for (int c = 0; c < COB; ++c)
#pragma unroll
        for (int p = 0; p < PXT; ++p) acc[c][p] = 0.f;

    const int iy0 = oy * STRIDE - ((STRIDE == 1) ? 1 : 0);
    const int ixb = oxb * STRIDE - ((STRIDE == 1) ? 1 : 0);

    for (int ci = ci0; ci < ci0 + CICHUNK; ++ci) {
#pragma unroll
        for (int ky = 0; ky < 3; ++ky) {
            const int iy = iy0 + ky;
            const float* __restrict__ rp = in + ((size_t)ci * HIN + iy) * WIN;
            float c[NCOL];
            if (iy >= 0 && iy < HIN) {
                if constexpr (STRIDE == 2) {
                    const float4 q0 = *reinterpret_cast<const float4*>(rp + ixb);
                    const float4 q1 = *reinterpret_cast<const float4*>(rp + ixb + 4);
                    c[0] = q0.x; c[1] = q0.y; c[2] = q0.z; c[3] = q0.w;
                    c[4] = q1.x; c[5] = q1.y; c[6] = q1.z; c[7] = q1.w;
                    c[8] = (ixb + 8 < WIN) ? rp[ixb + 8] : 0.f;
                } else {
                    c[0] = (ixb >= 0) ? rp[ixb] : 0.f;
                    c[1] = rp[ixb + 1];
                    c[2] = (ixb + 2 < WIN) ? rp[ixb + 2] : 0.f;
                }
            } else {
#pragma unroll
                for (int k = 0; k < NCOL; ++k) c[k] = 0.f;
            }
            // wave-uniform weight index -> s_load + SGPR-operand FMA
#pragma unroll
            for (int co = 0; co < COB; ++co) {
                const float* __restrict__ wp = w + (((size_t)(co0 + co) * CIN + ci) * 3 + ky) * 3;
#pragma unroll
                for (int kx = 0; kx < 3; ++kx) {
                    const float wv = wp[kx];
#pragma unroll
                    for (int p = 0; p < PXT; ++p)
                        acc[co][p] = fmaf(c[STRIDE * p + kx], wv, acc[co][p]);
                }
            }
        }
    }

    const int obase = oy * WOUT + oxb;
#pragma unroll
    for (int co = 0; co < COB; ++co) {
        float r[PXT];
#pragma unroll
        for (int p = 0; p < PXT; ++p) {
            r[p] = FUSEOUT ? fmaxf(acc[co][p] + bias[co0 + co], 0.f) : acc[co][p];
        }
        float* __restrict__ op = FUSEOUT
            ? out + (size_t)(co0 + co) * NPX + obase
            : out + ((size_t)blockIdx.z * CO + co0 + co) * NPX + obase;
        if constexpr (PXT == 4) {
            float4 q; q.x = r[0]; q.y = r[1]; q.z = r[2]; q.w = r[3];
            *reinterpret_cast<float4*>(op) = q;
        } else {
#pragma unroll
            for (int p = 0; p < PXT; ++p) op[p] = r[p];
        }
    }
}

// ---------------- chunk reduction + bias (+relu) ---------------------------
template<int NCHUNK, int NPX, bool RELU>
__global__ __launch_bounds__(256)
void reducek(const float* __restrict__ part, const float* __restrict__ bias,
             float* __restrict__ out, int CO)
{
    const int t = blockIdx.x * 256 + threadIdx.x;   // < CO*NPX
    const int co = t / NPX, px = t - co * NPX;
    float s = 0.f;
#pragma unroll
    for (int c = 0; c < NCHUNK; ++c) s += part[((size_t)c * CO + co) * NPX + px];
    s += bias[co];
    out[(size_t)co * NPX + px] = RELU ? fmaxf(s, 0.f) : s;
}

// ---------------- anchor decode + sortable key -----------------------------
__global__ void decode_kernel(const float* __restrict__ head,
                              float4* __restrict__ boxes,
                              unsigned long long* __restrict__ keys)
{
    const int i = blockIdx.x * 256 + threadIdx.x;    // < 12288
    const int a = i % 3;
    const int xy = i / 3;
    const int x = xy & 63, y = xy >> 6;
    const int px = y * 64 + x;

    const float t0 = head[(a * 5 + 0) * 4096 + px];
    const float t1 = head[(a * 5 + 1) * 4096 + px];
    const float t2 = head[(a * 5 + 2) * 4096 + px];
    const float t3 = head[(a * 5 + 3) * 4096 + px];
    const float lg = head[(a * 5 + 4) * 4096 + px];

    const float sz  = (a == 0) ? 32.f : (a == 1) ? 64.f : 128.f;
    const float cxa = (x + 0.5f) * 16.f;
    const float cya = (y + 0.5f) * 16.f;

    const float cx = __fadd_rn(cxa, __fmul_rn(t0, sz));
    const float cy = __fadd_rn(cya, __fmul_rn(t1, sz));
    const float bw = __fmul_rn(sz, expf(fminf(fmaxf(t2, -4.f), 4.f)));
    const float bh = __fmul_rn(sz, expf(fminf(fmaxf(t3, -4.f), 4.f)));
    const float hw = __fmul_rn(bw, 0.5f);
    const float hh = __fmul_rn(bh, 0.5f);

    float4 bb;
    bb.x = __fsub_rn(cx, hw);
    bb.y = __fsub_rn(cy, hh);
    bb.z = __fadd_rn(cx, hw);
    bb.w = __fadd_rn(cy, hh);
    boxes[i] = bb;

    const float score = 1.f / (1.f + expf(-lg));
    unsigned long long key = 0ull;
    if (score >= 0.5f) {  // positive float bits are order-preserving
        key = ((unsigned long long)__float_as_uint(score) << 32)
            | (unsigned long long)(0xFFFFFFFFu - (unsigned)i);  // stable tiebreak
    }
    keys[i] = key;
}

// ---------------- exact rank among all keys (j-split, readlane bcast) ------
constexpr int JSPLIT = 16;
constexpr int JCHUNK = NANCH / JSPLIT;   // 768

__global__ __launch_bounds__(256)
void rank_kernel(const unsigned long long* __restrict__ keys,
                 int* __restrict__ rank)
{
    const int i = blockIdx.x * 256 + threadIdx.x;
    const unsigned long long ki = keys[i];
    const int lane = threadIdx.x & 63;
    const int jbase = blockIdx.y * JCHUNK;

    int cnt = 0;
    for (int g = 0; g < JCHUNK / 64; ++g) {
        const unsigned long long kj = keys[jbase + g * 64 + lane];
        const unsigned lo0 = (unsigned)kj;
        const unsigned hi0 = (unsigned)(kj >> 32);
#pragma unroll
        for (int l = 0; l < 64; ++l) {
            const unsigned lo = (unsigned)__builtin_amdgcn_readlane((int)lo0, l);
            const unsigned hi = (unsigned)__builtin_amdgcn_readlane((int)hi0, l);
            const unsigned long long kjj = ((unsigned long long)hi << 32) | lo;
            cnt += (kjj > ki) ? 1 : 0;
        }
    }
    if (cnt) atomicAdd(&rank[i], cnt);   // int atomics: deterministic
}

__global__ void scatter_kernel(const unsigned long long* __restrict__ keys,
                               const int* __restrict__ rank,
                               const float4* __restrict__ boxes,
                               float4* __restrict__ selb, int* __restrict__ selv)
{
    const int i = blockIdx.x * 256 + threadIdx.x;
    if (keys[i] == 0ull) return;            // below score threshold
    const int r = rank[i];
    if (r < KTOP) { selb[r] = boxes[i]; selv[r] = 1; }
}

// ---------------- sequential NMS (exact reference semantics) ---------------
__global__ __launch_bounds__(128)
void nms_kernel(const float4* __restrict__ selb, const int* __restrict__ selv,
                float4* __restrict__ drawb)
{
    __shared__ float bx1[KTOP], by1[KTOP], bx2[KTOP], by2[KTOP], ar[KTOP];
    __shared__ int kp[KTOP];
    const int t = threadIdx.x;
    if (t < KTOP) {
        const float4 b = selb[t];
        bx1[t] = b.x; by1[t] = b.y; bx2[t] = b.z; by2[t] = b.w;
        ar[t] = (b.z - b.x) * (b.w - b.y);
        kp[t] = selv[t];
    }
    __syncthreads();
    for (int i = 0; i < KTOP - 1; ++i) {
        if (t > i && t < KTOP) {
            if (kp[i] && kp[t]) {
                const float lx = fmaxf(bx1[i], bx1[t]);
                const float ly = fmaxf(by1[i], by1[t]);
                const float rx = fminf(bx2[i], bx2[t]);
                const float ry = fminf(by2[i], by2[t]);
                const float ww = fmaxf(rx - lx, 0.f);
                const float hh = fmaxf(ry - ly, 0.f);
                const float inter = ww * hh;
                const float iou = inter / (ar[i] + ar[t] - inter + 1e-9f);
                if (iou > 0.5f) kp[t] = 0;
            }
        }
        __syncthreads();
    }
    if (t < KTOP) {
        float4 d;
        if (kp[t]) {
            d.x = fminf(fmaxf(bx1[t], 0.f), 1024.f);
            d.y = fminf(fmaxf(by1[t], 0.f), 1024.f);
            d.z = fminf(fmaxf(bx2[t], 0.f), 1024.f);
            d.w = fminf(fmaxf(by2[t], 0.f), 1024.f);
        } else {  // sentinel: never matches any pixel
            d.x = 3e9f; d.y = 3e9f; d.z = -3e9f; d.w = -3e9f;
        }
        drawb[t] = d;
    }
}

// ---------------- draw red borders -----------------------------------------
__global__ __launch_bounds__(256)
void draw_kernel(const float* __restrict__ frame,
                 const float4* __restrict__ drawb, float* __restrict__ out)
{
    const int y = blockIdx.x >> 2;
    const int x = ((blockIdx.x & 3) << 8) + threadIdx.x;
    const float fy = (float)y, fx = (float)x;

    bool mask = false;
#pragma unroll 1
    for (int b = 0; b < KTOP; ++b) {
        const float4 d = drawb[b];            // wave-uniform
        if (fy >= d.y && fy < d.w) {          // scalar branch: y-row inside box?
            const bool yinner = (fy >= d.y + 4.f) && (fy < d.w - 4.f);
            const bool xin    = (fx >= d.x) && (fx < d.z);
            const bool xinner = (fx >= d.x + 4.f) && (fx < d.z - 4.f);
            mask |= xin && !(yinner && xinner);
        }
    }
    const int p = y * 1024 + x;
    const float f0 = frame[p];
    const float f1 = frame[1048576 + p];
    const float f2 = frame[2097152 + p];
    out[p]           = mask ? 1.f : f0;
    out[1048576 + p] = mask ? 0.f : f1;
    out[2097152 + p] = mask ? 0.f : f2;
}

// ---------------------------------------------------------------------------
extern "C" void kernel_launch(void* const* d_in, const int* in_sizes, int n_in,
                              void* d_out, int out_size, void* d_ws, size_t ws_size,
                              hipStream_t stream)
{
    const float* frame = (const float*)d_in[0];
    const float* w1 = (const float*)d_in[1];  const float* b1 = (const float*)d_in[2];
    const float* w2 = (const float*)d_in[3];  const float* b2 = (const float*)d_in[4];
    const float* w3 = (const float*)d_in[5];  const float* b3 = (const float*)d_in[6];
    const float* w4 = (const float*)d_in[7];  const float* b4 = (const float*)d_in[8];
    const float* wh = (const float*)d_in[9];  const float* bh = (const float*)d_in[10];

    char* ws = (char*)d_ws;
    // Region A [0, 33.55M), Region B [33.55M, 50.33M). Lifetime audit:
    //  A: buf1[0,33.55) -> part3[0,16.78) -> buf3[16.78,25.17) ->
    //     part4[0,16.78) -> buf4[25.17,29.36) -> partH[0,15.73) -> heado[29.36,29.61)
    //  B: buf2[0,16.78) -> (dead after conv3) small detect buffers
    float* buf1  = (float*)ws;
    float* buf2  = (float*)(ws + 33554432);
    float* part3 = (float*)ws;                       // 2 x 8.39M
    float* buf3  = (float*)(ws + 16777216);
    float* part4 = (float*)ws;                       // 4 x 4.19M
    float* buf4  = (float*)(ws + 25165824);
    float* partH = (float*)ws;                       // 64 x 245K = 15.73M
    float* heado = (float*)(ws + 29360128);
    char*  B     = ws + 33554432;
    float4* boxes = (float4*)(B);                                  // 196608
    unsigned long long* keys = (unsigned long long*)(B + 196608);  // 98304
    int*    rankb = (int*)(B + 294912);                            // 49152
    int*    selv  = (int*)(B + 344064);                            // 512
    float4* selb  = (float4*)(B + 344576);                         // 1600
    float4* drawb = (float4*)(B + 346176);                         // 1600
    float*  outp  = (float*)d_out;

    // backbone: 4 px/thread, COB=4/8, grids = 1024 blocks (4/CU)
    convk<3, 1024, 1024, 2, 4, 8, 3,  true ><<<dim3(256,  4, 1), 256, 0, stream>>>(frame, w1, b1, buf1, 32);
    convk<32,  512,  512, 2, 4, 4, 32, true ><<<dim3(64,  16, 1), 256, 0, stream>>>(buf1, w2, b2, buf2, 64);
    convk<64,  256,  256, 2, 4, 4, 32, false><<<dim3(16,  32, 2), 256, 0, stream>>>(buf2, w3, nullptr, part3, 128);
    reducek<2, 16384, true><<<8192, 256, 0, stream>>>(part3, b3, buf3, 128);
    convk<128, 128,  128, 2, 4, 4, 32, false><<<dim3(4,   64, 4), 256, 0, stream>>>(buf3, w4, nullptr, part4, 256);
    reducek<4, 4096, true><<<4096, 256, 0, stream>>>(part4, b4, buf4, 256);

    // head (stride1, no relu): 1 px/thread, COB=15, ci chunks of 4
    convk<256, 64, 64, 1, 1, 15, 4, false><<<dim3(16, 1, 64), 256, 0, stream>>>(buf4, wh, nullptr, partH, 15);
    reducek<64, 4096, false><<<240, 256, 0, stream>>>(partH, bh, heado, 15);

    // zero rank+selv (B small-buffer region; buf2 dead)
    hipMemsetAsync(rankb, 0, 49152 + 512, stream);

    // decode + top-100 + nms + draw
    decode_kernel<<<48, 256, 0, stream>>>(heado, boxes, keys);
    rank_kernel<<<dim3(48, JSPLIT), 256, 0, stream>>>(keys, rankb);
    scatter_kernel<<<48, 256, 0, stream>>>(keys, rankb, boxes, selb, selv);
    nms_kernel<<<1, 128, 0, stream>>>(selb, selv, drawb);
    draw_kernel<<<4096, 256, 0, stream>>>(frame, drawb, outp);
}